// Round 17
// baseline (4904.012 us; speedup 1.0000x reference)
//
#include <hip/hip_runtime.h>

// R17 = R16 with the register budget actually pinned. R16's VGPR_Count=64
// revealed __launch_bounds__ 2nd arg = min BLOCKS/CU (CUDA semantics): (512,4)
// -> 32 waves/CU -> 64 VGPRs -> all U spilled (34 MB/step scratch refetch).
// Fix: (512,2) [16 waves/CU -> <=128 VGPR, still 2 blocks/CU co-resident] +
// amdgpu_waves_per_eu(4,4) to pin the allocator at the 128 budget. Demand
// ~118 fits. Chain pipeline 3x16 -> 3x8 to cut chain-thread pressure.
// Trajectory bit-identical to R9/R12-R16 (all passed absmax 0).

#define T_STEPS 128
#define NE 8192
#define NI 2048
#define NTOT 10240
#define BATCHES 32
#define SLICES 16
#define SE 512
#define SI 128
#define NT 512
#define NWB 320
#define DECAYF 0.904837429523468017578125f   // f32(exp(f32(-0.1)))

__device__ unsigned g_masks[2][BATCHES][NWB];   // parity spike masks
__device__ float    g_R[2][BATCHES][96];        // parity combined currents
__device__ unsigned g_cnt[BATCHES * 16];        // mask-arrival counters
__device__ unsigned g_step[BATCHES * 16];       // R-ready flags (monotonic)

#define MAC4(acc, rv, uv)                                   \
    acc = __fadd_rn(acc, __fmul_rn((rv).x, (uv).x));        \
    acc = __fadd_rn(acc, __fmul_rn((rv).y, (uv).y));        \
    acc = __fadd_rn(acc, __fmul_rn((rv).z, (uv).z));        \
    acc = __fadd_rn(acc, __fmul_rn((rv).w, (uv).w));

#define PIN4(vv) asm volatile("" : "+v"((vv).x), "+v"((vv).y), "+v"((vv).z), "+v"((vv).w));

__global__ __launch_bounds__(NT, 2) __attribute__((amdgpu_waves_per_eu(4, 4)))
void snn_v17(const float* __restrict__ ext,
             const float* __restrict__ U_ee, const float* __restrict__ V_ee,
             const float* __restrict__ U_ei, const float* __restrict__ V_ei,
             const float* __restrict__ U_ie, const float* __restrict__ V_ie,
             float* __restrict__ out)
{
    __shared__ float sR1[32], sR2[32], sR3[32];
    __shared__ unsigned mw[NWB], pc[NWB];
    __shared__ unsigned short sIdxE[NE + 48];
    __shared__ unsigned short sIdxI[NI + 48];
    __shared__ int sCe, sCi;

    const int tid = threadIdx.x;
    const int b = blockIdx.x / SLICES;
    const int s = blockIdx.x % SLICES;
    const bool desig = (s == (b & 15));   // one chain-runner per batch -> XCD b%8

    // ---- this thread's U rows in registers (96 VGPRs; fits the 128 budget) ----
    float4 uA[8], uB[8], uC[8];
    {
        const float4* ap = (const float4*)(U_ee + ((size_t)s * SE + tid) * 32);
        const float4* bp = (const float4*)(U_ie + ((size_t)s * SE + tid) * 32);
        #pragma unroll
        for (int q = 0; q < 8; ++q) { uA[q] = ap[q]; uB[q] = bp[q]; }
        if (tid < SI) {
            const float4* cp = (const float4*)(U_ei + ((size_t)s * SI + tid) * 32);
            #pragma unroll
            for (int q = 0; q < 8; ++q) uC[q] = cp[q];
        } else {
            #pragma unroll
            for (int q = 0; q < 8; ++q) uC[q] = make_float4(0.f, 0.f, 0.f, 0.f);
        }
        #pragma unroll
        for (int q = 0; q < 8; ++q) { PIN4(uA[q]) PIN4(uB[q]) PIN4(uC[q]) }
    }
    if (tid < 32) { sR1[tid] = 0.f; sR2[tid] = 0.f; sR3[tid] = 0.f; }
    __syncthreads();

    float v0 = 0.f, vi = 0.f;
    int a0 = 0, ai = 0;
    unsigned* c1  = &g_cnt[b * 16];
    unsigned* stp = &g_step[b * 16];

    for (int t = 0; t < T_STEPS; ++t) {
        const int par = t & 1;
        unsigned* gm = &g_masks[par][b][0];

        // ================= Phase E (order identical to R9/R12-R16) =================
        bool sp0, spi = false;
        {
            const float xe0 = ext[((size_t)b * T_STEPS + t) * NE + (size_t)s * SE + tid];
            float t1 = 0.f, t2 = 0.f;
            #pragma unroll
            for (int q = 0; q < 8; ++q) {
                const float4 r1 = *(const float4*)&sR1[4 * q];
                const float4 r3 = *(const float4*)&sR3[4 * q];
                MAC4(t1, r1, uA[q])
                MAC4(t2, r3, uB[q])
            }
            const float I0 = __fadd_rn(__fadd_rn(t1, t2), xe0);
            v0 = __fadd_rn(__fmul_rn(v0, DECAYF), I0);
            sp0 = (v0 >= 1.0f); a0 += sp0 ? 1 : 0; if (sp0) v0 = 0.f;

            if (tid < SI) {
                float t3 = 0.f;
                #pragma unroll
                for (int q = 0; q < 8; ++q) {
                    const float4 r2 = *(const float4*)&sR2[4 * q];
                    MAC4(t3, r2, uC[q])
                }
                vi = __fadd_rn(__fmul_rn(vi, DECAYF), t3);
                spi = (vi >= 1.0f); ai += spi ? 1 : 0; if (spi) vi = 0.f;
            }
        }
        if (t == T_STEPS - 1) break;

        // ================= publish slice masks to LLC =================
        {
            const int wv = tid >> 6;
            const unsigned long long bal0 = __ballot(sp0);
            if ((tid & 63) == 0)
                __hip_atomic_store(&gm[s*16 + 2*wv],     (unsigned)bal0,         __ATOMIC_RELAXED, __HIP_MEMORY_SCOPE_AGENT);
            if ((tid & 63) == 32)
                __hip_atomic_store(&gm[s*16 + 2*wv + 1], (unsigned)(bal0 >> 32), __ATOMIC_RELAXED, __HIP_MEMORY_SCOPE_AGENT);
            if (tid < SI) {   // waves 0,1 entirely -> wave-uniform branch
                const unsigned long long bi2 = __ballot(spi);
                if ((tid & 63) == 0)
                    __hip_atomic_store(&gm[256 + s*4 + 2*wv],     (unsigned)bi2,         __ATOMIC_RELAXED, __HIP_MEMORY_SCOPE_AGENT);
                if ((tid & 63) == 32)
                    __hip_atomic_store(&gm[256 + s*4 + 2*wv + 1], (unsigned)(bi2 >> 32), __ATOMIC_RELAXED, __HIP_MEMORY_SCOPE_AGENT);
            }
        }
        asm volatile("s_waitcnt vmcnt(0)" ::: "memory");
        __syncthreads();
        if (tid == 0)
            __hip_atomic_fetch_add(c1, 1u, __ATOMIC_RELAXED, __HIP_MEMORY_SCOPE_AGENT);

        if (desig) {
            if (tid == 0) {
                const unsigned target = (unsigned)SLICES * (unsigned)(t + 1);
                while (__hip_atomic_load(c1, __ATOMIC_RELAXED, __HIP_MEMORY_SCOPE_AGENT) < target)
                    __builtin_amdgcn_s_sleep(1);
            }
            __syncthreads();
            if (tid < NWB)
                mw[tid] = __hip_atomic_load(&gm[tid], __ATOMIC_RELAXED, __HIP_MEMORY_SCOPE_AGENT);
            __syncthreads();
            if (tid < NWB) pc[tid] = (unsigned)__popc(mw[tid]);
            __syncthreads();
            for (int d = 1; d < 256; d <<= 1) {
                unsigned add = 0u; bool act = false;
                if (tid < 256)      { if (tid >= d)       { add = pc[tid - d]; act = true; } }
                else if (tid < NWB) { if (tid - 256 >= d) { add = pc[tid - d]; act = true; } }
                __syncthreads();
                if (act) pc[tid] += add;
                __syncthreads();
            }
            if (tid == 0)  sCe = (int)pc[255];
            if (tid == 64) sCi = (int)pc[319];
            __syncthreads();
            if (tid < NWB) {
                unsigned m = mw[tid];
                int off = (int)pc[tid] - __popc(m);
                if (tid < 256) {
                    const unsigned nb = (unsigned)tid * 32u;
                    while (m) { const int bit = __ffs(m) - 1; m &= m - 1;
                        sIdxE[off++] = (unsigned short)(nb + (unsigned)bit); }
                } else {
                    const unsigned nb = (unsigned)(tid - 256) * 32u;
                    while (m) { const int bit = __ffs(m) - 1; m &= m - 1;
                        sIdxI[off++] = (unsigned short)(nb + (unsigned)bit); }
                }
            }
            if (tid >= 320 && tid < 368)      sIdxE[sCe + (tid - 320)] = 0;
            else if (tid >= 384 && tid < 432) sIdxI[sCi + (tid - 384)] = 0;
            __syncthreads();
            // ---- serial chains, 3-deep x8 pipeline (ascending order preserved) ----
            if (tid < 96) {
                const int tb = tid >> 5;
                const int r = tid & 31;
                const float* __restrict__ V = ((tb == 0) ? V_ee : (tb == 1) ? V_ei : V_ie) + r;
                const unsigned short* __restrict__ ip = (tb == 2) ? sIdxI : sIdxE;
                const int cnt2 = (tb == 2) ? sCi : sCe;
                const int full = cnt2 >> 3;
                const int tail = cnt2 & 7;
                float a = 0.f;
                float xa[8], xb[8], xc[8];
                #pragma unroll
                for (int u = 0; u < 8; ++u) xa[u] = V[(unsigned)ip[u] * 32u];
                #pragma unroll
                for (int u = 0; u < 8; ++u) xb[u] = V[(unsigned)ip[8 + u] * 32u];
                #pragma unroll
                for (int u = 0; u < 8; ++u) xc[u] = V[(unsigned)ip[16 + u] * 32u];
                int g = 0;
                for (; g + 3 <= full; g += 3) {
                    #pragma unroll
                    for (int u = 0; u < 8; ++u) a = __fadd_rn(a, xa[u]);
                    #pragma unroll
                    for (int u = 0; u < 8; ++u) xa[u] = V[(unsigned)ip[(g + 3) * 8 + u] * 32u];
                    #pragma unroll
                    for (int u = 0; u < 8; ++u) a = __fadd_rn(a, xb[u]);
                    #pragma unroll
                    for (int u = 0; u < 8; ++u) xb[u] = V[(unsigned)ip[(g + 4) * 8 + u] * 32u];
                    #pragma unroll
                    for (int u = 0; u < 8; ++u) a = __fadd_rn(a, xc[u]);
                    #pragma unroll
                    for (int u = 0; u < 8; ++u) xc[u] = V[(unsigned)ip[(g + 5) * 8 + u] * 32u];
                }
                const int rem = full - g;
                if (rem == 0) {
                    #pragma unroll
                    for (int u = 0; u < 8; ++u) if (u < tail) a = __fadd_rn(a, xa[u]);
                } else if (rem == 1) {
                    #pragma unroll
                    for (int u = 0; u < 8; ++u) a = __fadd_rn(a, xa[u]);
                    #pragma unroll
                    for (int u = 0; u < 8; ++u) if (u < tail) a = __fadd_rn(a, xb[u]);
                } else {
                    #pragma unroll
                    for (int u = 0; u < 8; ++u) a = __fadd_rn(a, xa[u]);
                    #pragma unroll
                    for (int u = 0; u < 8; ++u) a = __fadd_rn(a, xb[u]);
                    #pragma unroll
                    for (int u = 0; u < 8; ++u) if (u < tail) a = __fadd_rn(a, xc[u]);
                }
                ((tb == 0) ? sR1 : (tb == 1) ? sR2 : sR3)[r] = a;
                __hip_atomic_store(&g_R[par][b][tid], a, __ATOMIC_RELAXED, __HIP_MEMORY_SCOPE_AGENT);
            }
            asm volatile("s_waitcnt vmcnt(0)" ::: "memory");
            __syncthreads();
            if (tid == 0)
                __hip_atomic_store(stp, (unsigned)(t + 1), __ATOMIC_RELAXED, __HIP_MEMORY_SCOPE_AGENT);
        } else {
            if (tid == 0) {
                while (__hip_atomic_load(stp, __ATOMIC_RELAXED, __HIP_MEMORY_SCOPE_AGENT) < (unsigned)(t + 1))
                    __builtin_amdgcn_s_sleep(1);
            }
            __syncthreads();
            if (tid < 96) {
                const float x = __hip_atomic_load(&g_R[par][b][tid], __ATOMIC_RELAXED, __HIP_MEMORY_SCOPE_AGENT);
                const int tb = tid >> 5;
                ((tb == 0) ? sR1 : (tb == 1) ? sR2 : sR3)[tid & 31] = x;
            }
            __syncthreads();
        }
    }

    // ================= outputs: spike counts [B][Ne+Ni] =================
    {
        float* ob = out + (size_t)b * NTOT;
        ob[(size_t)s * SE + tid] = (float)a0;
        if (tid < SI) ob[NE + (size_t)s * SI + tid] = (float)ai;
    }
}

extern "C" void kernel_launch(void* const* d_in, const int* in_sizes, int n_in,
                              void* d_out, int out_size, void* d_ws, size_t ws_size,
                              hipStream_t stream) {
    (void)in_sizes; (void)n_in; (void)d_ws; (void)ws_size; (void)out_size;
    const float* ext  = (const float*)d_in[0];
    const float* U_ee = (const float*)d_in[1];
    const float* V_ee = (const float*)d_in[2];
    const float* U_ei = (const float*)d_in[3];
    const float* V_ei = (const float*)d_in[4];
    const float* U_ie = (const float*)d_in[5];
    const float* V_ie = (const float*)d_in[6];

    void* p = nullptr;
    hipGetSymbolAddress(&p, HIP_SYMBOL(g_cnt));
    hipMemsetAsync(p, 0, sizeof(unsigned) * BATCHES * 16, stream);
    hipGetSymbolAddress(&p, HIP_SYMBOL(g_step));
    hipMemsetAsync(p, 0, sizeof(unsigned) * BATCHES * 16, stream);

    snn_v17<<<dim3(BATCHES * SLICES), dim3(NT), 0, stream>>>(
        ext, U_ee, V_ee, U_ei, V_ei, U_ie, V_ie, (float*)d_out);
}

// Round 18
// 3850.595 us; speedup vs baseline: 1.2736x; 1.2736x over previous
//
#include <hip/hip_runtime.h>

// R18: kill the sync critical path (R13-R17 invariant 33-39us/step despite
// 40x FETCH swings = latency-bound, not memory-bound).
//  - ONE sync/step: all blocks redundantly compact+chain (V is L2-resident)
//  - per-slice flag lines (parallel polls) replace 16 serialized atomic RMWs
//  - 256 blk = 32 batch x 8 slices x 1024 thr; 1 e-neuron/thread (U<=96 regs)
//  - chain on no-uC waves with 3x16 pipeline (lookahead ~ L2 latency)
//  - wave-shfl scan compaction (2 barriers); ext(t+1) prefetch under poll
// Trajectory bit-identical to R9/R12-R17 (all passed absmax 0).

#define T_STEPS 128
#define NE 8192
#define NI 2048
#define NTOT 10240
#define BATCHES 32
#define SLICES 8
#define SE 1024
#define SI 256
#define NT 1024
#define NWB 320
#define DECAYF 0.904837429523468017578125f   // f32(exp(f32(-0.1)))

__device__ unsigned g_masks[2][BATCHES][NWB];     // parity spike masks
__device__ unsigned g_flag[BATCHES][SLICES][16];  // per-slice flags, 64B apart

#define MAC4(acc, rv, uv)                                   \
    acc = __fadd_rn(acc, __fmul_rn((rv).x, (uv).x));        \
    acc = __fadd_rn(acc, __fmul_rn((rv).y, (uv).y));        \
    acc = __fadd_rn(acc, __fmul_rn((rv).z, (uv).z));        \
    acc = __fadd_rn(acc, __fmul_rn((rv).w, (uv).w));

#define PIN4(vv) asm volatile("" : "+v"((vv).x), "+v"((vv).y), "+v"((vv).z), "+v"((vv).w));

__global__ __launch_bounds__(NT, 1) __attribute__((amdgpu_waves_per_eu(4, 4)))
void snn_v18(const float* __restrict__ ext,
             const float* __restrict__ U_ee, const float* __restrict__ V_ee,
             const float* __restrict__ U_ei, const float* __restrict__ V_ei,
             const float* __restrict__ U_ie, const float* __restrict__ V_ie,
             float* __restrict__ out)
{
    __shared__ float sR1[32], sR2[32], sR3[32];
    __shared__ unsigned mw[NWB], pc[NWB];
    __shared__ unsigned short sIdxE[NE + 48];
    __shared__ unsigned short sIdxI[NI + 48];
    __shared__ int sCe, sCi;

    const int tid = threadIdx.x;
    const int b = blockIdx.x & 31;    // batch: slices of batch b share XCD b%8
    const int s = blockIdx.x >> 5;    // slice

    // ---- this thread's U rows in registers ----
    float4 uA[8], uB[8], uC[8];
    {
        const float4* ap = (const float4*)(U_ee + ((size_t)s * SE + tid) * 32);
        const float4* bp = (const float4*)(U_ie + ((size_t)s * SE + tid) * 32);
        #pragma unroll
        for (int q = 0; q < 8; ++q) { uA[q] = ap[q]; uB[q] = bp[q]; }
        if (tid < SI) {
            const float4* cp = (const float4*)(U_ei + ((size_t)s * SI + tid) * 32);
            #pragma unroll
            for (int q = 0; q < 8; ++q) uC[q] = cp[q];
        } else {
            #pragma unroll
            for (int q = 0; q < 8; ++q) uC[q] = make_float4(0.f, 0.f, 0.f, 0.f);
        }
        #pragma unroll
        for (int q = 0; q < 8; ++q) { PIN4(uA[q]) PIN4(uB[q]) }
        if (tid < SI) {
            #pragma unroll
            for (int q = 0; q < 8; ++q) { PIN4(uC[q]) }
        }
    }
    if (tid < 32) { sR1[tid] = 0.f; sR2[tid] = 0.f; sR3[tid] = 0.f; }
    __syncthreads();

    float v0 = 0.f, vi = 0.f;
    int a0 = 0, ai = 0;
    float xe_cur = ext[((size_t)b * T_STEPS + 0) * NE + (size_t)s * SE + tid];

    for (int t = 0; t < T_STEPS; ++t) {
        const int par = t & 1;
        unsigned* gm = &g_masks[par][b][0];

        // ================= Phase E (order identical to R9/R12-R17) =================
        bool sp0, spi = false;
        {
            float t1 = 0.f, t2 = 0.f;
            #pragma unroll
            for (int q = 0; q < 8; ++q) {
                const float4 r1 = *(const float4*)&sR1[4 * q];
                const float4 r3 = *(const float4*)&sR3[4 * q];
                MAC4(t1, r1, uA[q])
                MAC4(t2, r3, uB[q])
            }
            const float I0 = __fadd_rn(__fadd_rn(t1, t2), xe_cur);
            v0 = __fadd_rn(__fmul_rn(v0, DECAYF), I0);
            sp0 = (v0 >= 1.0f); a0 += sp0 ? 1 : 0; if (sp0) v0 = 0.f;

            if (tid < SI) {
                float t3 = 0.f;
                #pragma unroll
                for (int q = 0; q < 8; ++q) {
                    const float4 r2 = *(const float4*)&sR2[4 * q];
                    MAC4(t3, r2, uC[q])
                }
                vi = __fadd_rn(__fmul_rn(vi, DECAYF), t3);
                spi = (vi >= 1.0f); ai += spi ? 1 : 0; if (spi) vi = 0.f;
            }
        }
        if (t == T_STEPS - 1) break;

        // ================= publish slice masks to LLC =================
        {
            const int wv = tid >> 6;   // 0..15
            const unsigned long long bal0 = __ballot(sp0);
            if ((tid & 63) == 0)
                __hip_atomic_store(&gm[s*32 + 2*wv],     (unsigned)bal0,         __ATOMIC_RELAXED, __HIP_MEMORY_SCOPE_AGENT);
            if ((tid & 63) == 32)
                __hip_atomic_store(&gm[s*32 + 2*wv + 1], (unsigned)(bal0 >> 32), __ATOMIC_RELAXED, __HIP_MEMORY_SCOPE_AGENT);
            if (tid < SI) {   // waves 0..3 entirely -> wave-uniform
                const unsigned long long bi2 = __ballot(spi);
                if ((tid & 63) == 0)
                    __hip_atomic_store(&gm[256 + s*8 + 2*wv],     (unsigned)bi2,         __ATOMIC_RELAXED, __HIP_MEMORY_SCOPE_AGENT);
                if ((tid & 63) == 32)
                    __hip_atomic_store(&gm[256 + s*8 + 2*wv + 1], (unsigned)(bi2 >> 32), __ATOMIC_RELAXED, __HIP_MEMORY_SCOPE_AGENT);
            }
        }
        asm volatile("s_waitcnt vmcnt(0)" ::: "memory");   // per-wave store drain
        __syncthreads();
        if (tid == 0)
            __hip_atomic_store(&g_flag[b][s][0], (unsigned)(t + 1), __ATOMIC_RELAXED, __HIP_MEMORY_SCOPE_AGENT);
        // prefetch next ext while sync/compact/chain run (t+1 <= T-1 here)
        xe_cur = ext[((size_t)b * T_STEPS + (t + 1)) * NE + (size_t)s * SE + tid];

        // ================= poll all 8 slice flags (parallel lanes) =================
        if (tid < SLICES) {
            while (__hip_atomic_load(&g_flag[b][tid][0], __ATOMIC_RELAXED, __HIP_MEMORY_SCOPE_AGENT) < (unsigned)(t + 1))
                __builtin_amdgcn_s_sleep(1);
        }
        __syncthreads();

        // ================= read masks + popc =================
        if (tid < NWB) {
            const unsigned m = __hip_atomic_load(&gm[tid], __ATOMIC_RELAXED, __HIP_MEMORY_SCOPE_AGENT);
            mw[tid] = m;
            pc[tid] = (unsigned)__popc(m);
        }
        __syncthreads();

        // ================= wave-shuffle segmented scan (e: 256 words, i: 64) =====
        if (tid < 64) {
            const unsigned s0 = pc[4*tid], s1 = pc[4*tid+1], s2 = pc[4*tid+2], s3 = pc[4*tid+3];
            const unsigned q0 = s0, q1 = q0 + s1, q2 = q1 + s2, q3 = q2 + s3;
            unsigned tot = q3;
            #pragma unroll
            for (int d = 1; d < 64; d <<= 1) {
                const unsigned vsh = __shfl_up(tot, d, 64);
                if (tid >= d) tot += vsh;
            }
            const unsigned base = tot - q3;
            pc[4*tid] = base + q0; pc[4*tid+1] = base + q1;
            pc[4*tid+2] = base + q2; pc[4*tid+3] = base + q3;
        } else if (tid < 128) {
            const int L = tid - 64;
            unsigned tot = pc[256 + L];
            #pragma unroll
            for (int d = 1; d < 64; d <<= 1) {
                const unsigned vsh = __shfl_up(tot, d, 64);
                if (L >= d) tot += vsh;
            }
            pc[256 + L] = tot;
        }
        __syncthreads();

        // ================= expand (order-preserving) + counts =================
        if (tid < NWB) {
            unsigned m = mw[tid];
            int off = (int)pc[tid] - __popc(m);
            if (tid < 256) {
                const unsigned nb = (unsigned)tid * 32u;
                while (m) { const int bit = __ffs(m) - 1; m &= m - 1;
                    sIdxE[off++] = (unsigned short)(nb + (unsigned)bit); }
            } else {
                const unsigned nb = (unsigned)(tid - 256) * 32u;
                while (m) { const int bit = __ffs(m) - 1; m &= m - 1;
                    sIdxI[off++] = (unsigned short)(nb + (unsigned)bit); }
            }
        }
        if (tid == 320) sCe = (int)pc[255];
        if (tid == 321) sCi = (int)pc[319];
        __syncthreads();

        // ================= pad for chain lookahead =================
        if (tid < 48)                    sIdxE[sCe + tid] = 0;
        else if (tid >= 64 && tid < 112) sIdxI[sCi + (tid - 64)] = 0;
        __syncthreads();

        // ===== serial chains, 3x16 pipeline, on low-pressure waves (no uC) =====
        if (tid >= 768 && tid < 960 && (tid & 63) < 32) {
            const int tb = (tid - 768) >> 6;   // 0: V_ee, 1: V_ei, 2: V_ie
            const int r = tid & 31;
            const float* __restrict__ V = ((tb == 0) ? V_ee : (tb == 1) ? V_ei : V_ie) + r;
            const unsigned short* __restrict__ ip = (tb == 2) ? sIdxI : sIdxE;
            const int cnt2 = (tb == 2) ? sCi : sCe;
            const int full = cnt2 >> 4;
            const int tail = cnt2 & 15;
            float a = 0.f;
            float xa[16], xb[16], xc[16];
            #pragma unroll
            for (int u = 0; u < 16; ++u) xa[u] = V[(unsigned)ip[u] * 32u];
            #pragma unroll
            for (int u = 0; u < 16; ++u) xb[u] = V[(unsigned)ip[16 + u] * 32u];
            #pragma unroll
            for (int u = 0; u < 16; ++u) xc[u] = V[(unsigned)ip[32 + u] * 32u];
            int g = 0;
            for (; g + 3 <= full; g += 3) {
                #pragma unroll
                for (int u = 0; u < 16; ++u) a = __fadd_rn(a, xa[u]);
                #pragma unroll
                for (int u = 0; u < 16; ++u) xa[u] = V[(unsigned)ip[(g + 3) * 16 + u] * 32u];
                #pragma unroll
                for (int u = 0; u < 16; ++u) a = __fadd_rn(a, xb[u]);
                #pragma unroll
                for (int u = 0; u < 16; ++u) xb[u] = V[(unsigned)ip[(g + 4) * 16 + u] * 32u];
                #pragma unroll
                for (int u = 0; u < 16; ++u) a = __fadd_rn(a, xc[u]);
                #pragma unroll
                for (int u = 0; u < 16; ++u) xc[u] = V[(unsigned)ip[(g + 5) * 16 + u] * 32u];
            }
            const int rem = full - g;
            if (rem == 0) {
                #pragma unroll
                for (int u = 0; u < 16; ++u) if (u < tail) a = __fadd_rn(a, xa[u]);
            } else if (rem == 1) {
                #pragma unroll
                for (int u = 0; u < 16; ++u) a = __fadd_rn(a, xa[u]);
                #pragma unroll
                for (int u = 0; u < 16; ++u) if (u < tail) a = __fadd_rn(a, xb[u]);
            } else {
                #pragma unroll
                for (int u = 0; u < 16; ++u) a = __fadd_rn(a, xa[u]);
                #pragma unroll
                for (int u = 0; u < 16; ++u) a = __fadd_rn(a, xb[u]);
                #pragma unroll
                for (int u = 0; u < 16; ++u) if (u < tail) a = __fadd_rn(a, xc[u]);
            }
            ((tb == 0) ? sR1 : (tb == 1) ? sR2 : sR3)[r] = a;
        }
        __syncthreads();
    }

    // ================= outputs: spike counts [B][Ne+Ni] =================
    {
        float* ob = out + (size_t)b * NTOT;
        ob[(size_t)s * SE + tid] = (float)a0;
        if (tid < SI) ob[NE + (size_t)s * SI + tid] = (float)ai;
    }
}

extern "C" void kernel_launch(void* const* d_in, const int* in_sizes, int n_in,
                              void* d_out, int out_size, void* d_ws, size_t ws_size,
                              hipStream_t stream) {
    (void)in_sizes; (void)n_in; (void)d_ws; (void)ws_size; (void)out_size;
    const float* ext  = (const float*)d_in[0];
    const float* U_ee = (const float*)d_in[1];
    const float* V_ee = (const float*)d_in[2];
    const float* U_ei = (const float*)d_in[3];
    const float* V_ei = (const float*)d_in[4];
    const float* U_ie = (const float*)d_in[5];
    const float* V_ie = (const float*)d_in[6];

    void* p = nullptr;
    hipGetSymbolAddress(&p, HIP_SYMBOL(g_flag));
    hipMemsetAsync(p, 0, sizeof(unsigned) * BATCHES * SLICES * 16, stream);

    snn_v18<<<dim3(BATCHES * SLICES), dim3(NT), 0, stream>>>(
        ext, U_ee, V_ee, U_ei, V_ei, U_ie, V_ie, (float*)d_out);
}